// Round 2
// baseline (336.527 us; speedup 1.0000x reference)
//
#include <hip/hip_runtime.h>
#include <hip/hip_bf16.h>

#define B_N 8
#define C_IN 512
#define C_OUT 512
#define H_ 64
#define W_ 64
#define HW_ 4096
#define LAT_ 512

typedef __attribute__((ext_vector_type(8))) short bf8;
typedef __attribute__((ext_vector_type(4))) float f32x4;

__device__ inline ushort f2bf(float f) {
  uint u = __float_as_uint(f);
  uint r = (u + 0x7FFFu + ((u >> 16) & 1u)) >> 16;
  return (ushort)r;
}

// ---------------- style[b][cin] = latent @ (fcw * LAT^-0.5)^T + fcb ----------------
__global__ void style_kernel(const float* __restrict__ latent,
                             const float* __restrict__ fcw,
                             const float* __restrict__ fcb,
                             float* __restrict__ style) {
  int idx = blockIdx.x * blockDim.x + threadIdx.x;  // 4096
  int b = idx >> 9, c = idx & 511;
  const float4* l4 = (const float4*)(latent + b * LAT_);
  const float4* w4 = (const float4*)(fcw + (size_t)c * LAT_);
  float acc = 0.f;
#pragma unroll 4
  for (int i = 0; i < LAT_ / 4; ++i) {
    float4 a = l4[i], w = w4[i];
    acc += a.x * w.x + a.y * w.y + a.z * w.z + a.w * w.w;
  }
  style[idx] = acc * 0.04419417382415922f + fcb[c];  // 1/sqrt(512)
}

// ---------------- wsq[cout][cin] = sum_{kh,kw} weight^2 ----------------
__global__ void wsq_kernel(const float* __restrict__ w, float* __restrict__ wsq) {
  int idx = blockIdx.x * blockDim.x + threadIdx.x;  // 262144
  const float* p = w + (size_t)idx * 9;
  float s = 0.f;
#pragma unroll
  for (int t = 0; t < 9; ++t) s += p[t] * p[t];
  wsq[idx] = s;
}

// ---------------- demod[b][cout] = rsqrt(sum_cin style^2 * wsq + eps) * (1/48) ----------------
__global__ void demod_kernel(const float* __restrict__ style,
                             const float* __restrict__ wsq,
                             float* __restrict__ demod) {
  int idx = blockIdx.x * blockDim.x + threadIdx.x;  // 4096
  int b = idx >> 9, co = idx & 511;
  const float4* s4 = (const float4*)(style + (size_t)b * C_IN);
  const float4* w4 = (const float4*)(wsq + (size_t)co * C_IN);
  float acc = 0.f;
#pragma unroll 4
  for (int i = 0; i < C_IN / 4; ++i) {
    float4 s = s4[i], w = w4[i];
    acc += s.x * s.x * w.x + s.y * s.y * w.y + s.z * s.z * w.z + s.w * s.w * w.w;
  }
  // fold w_mul_conv = sqrt(2)/sqrt(512*9) = 1/48
  demod[idx] = rsqrtf(acc + 1e-8f) * 0.020833333333333332f;
}

// ---------------- wbf[tap][cout][cin] = bf16(weight[cout][cin][kh][kw]) ----------------
__global__ void wcast_kernel(const float* __restrict__ w, ushort* __restrict__ wbf) {
  int idx = blockIdx.x * blockDim.x + threadIdx.x;  // 262144 = cout*512+cin
  int cout = idx >> 9, cin = idx & 511;
  const float* p = w + (size_t)idx * 9;
#pragma unroll
  for (int t = 0; t < 9; ++t)
    wbf[((size_t)t * C_OUT + cout) * C_IN + cin] = f2bf(p[t]);
}

// ---------------- xm[b][h][w][cin] = bf16(x[b][cin][h][w] * style[b][cin])  (NCHW->NHWC) ----------------
__global__ void xmod_kernel(const float* __restrict__ x,
                            const float* __restrict__ style,
                            ushort* __restrict__ xm) {
  __shared__ float t[64][65];
  int c0 = blockIdx.x * 64;
  int h = blockIdx.y;
  int b = blockIdx.z;
  int tid = threadIdx.x;
  int col = tid & 63;
  int rg = tid >> 6;  // 0..3
#pragma unroll
  for (int rr = 0; rr < 16; ++rr) {
    int r = rr * 4 + rg;  // cin-local
    t[r][col] = x[(((size_t)(b * C_IN + c0 + r)) * H_ + h) * W_ + col] *
                style[b * C_IN + c0 + r];
  }
  __syncthreads();
#pragma unroll
  for (int rr = 0; rr < 16; ++rr) {
    int w = rr * 4 + rg;
    xm[(((size_t)(b * H_ + h)) * W_ + w) * C_IN + c0 + col] = f2bf(t[col][w]);
  }
}

// ---------------- main conv: per-batch implicit GEMM, 128x128 tile ----------------
#define BM 128
#define BK 64
#define AP 72     // padded cin stride in LDS (elems): 144B rows -> bank-uniform b128
#define BROWS 4
#define BCOLS 66

__global__ __launch_bounds__(256, 2)
void conv_kernel(const ushort* __restrict__ xm,
                 const ushort* __restrict__ wbf,
                 const float* __restrict__ demod,
                 const float* __restrict__ bias,
                 float* __restrict__ out) {
  __shared__ ushort As[BM * AP];            // 18432 B
  __shared__ ushort Bs[BROWS * BCOLS * AP]; // 38016 B

  const int tid = threadIdx.x;
  const int lane = tid & 63;
  const int wave = tid >> 6;
  const int wr = wave >> 1;  // cout 64-block
  const int wc = wave & 1;   // spatial 64-block
  const int l15 = lane & 15;
  const int kg = lane >> 4;  // 0..3

  const int cout0 = blockIdx.x * BM;
  const int tile = blockIdx.y;  // 0..31 (2 output rows each)
  const int b = blockIdx.z;
  const int r0 = tile * 2;

  const int sub = tid & 7;
  const int pr = tid >> 3;  // 0..31

  f32x4 acc[4][4];
#pragma unroll
  for (int m = 0; m < 4; ++m)
#pragma unroll
    for (int n = 0; n < 4; ++n) acc[m][n] = (f32x4){0.f, 0.f, 0.f, 0.f};

  const ushort* xb = xm + (size_t)b * HW_ * C_IN;

  // per-thread fragment LDS bases (element units)
  int aOff[4];
#pragma unroll
  for (int m = 0; m < 4; ++m) aOff[m] = (wr * 64 + m * 16 + l15) * AP + kg * 8;
  int bOff[4];
#pragma unroll
  for (int n = 0; n < 4; ++n) {
    int pl = wc * 64 + n * 16 + l15;
    bOff[n] = ((pl >> 6) * BCOLS + (pl & 63)) * AP + kg * 8;
  }

  const bf8 zer = {0, 0, 0, 0, 0, 0, 0, 0};

  for (int cin0 = 0; cin0 < C_IN; cin0 += BK) {
    __syncthreads();
    // ---- stage B tile: 4 halo rows x 64 cols x 64 cin (zero-padded) ----
#pragma unroll
    for (int pass = 0; pass < 8; ++pass) {
      int pair = pass * 32 + pr;
      int row = pair >> 6;   // 0..3
      int col = pair & 63;
      int gr = r0 - 1 + row;
      bf8* dst = (bf8*)&Bs[(row * BCOLS + col + 1) * AP + sub * 8];
      if ((unsigned)gr < (unsigned)H_) {
        *dst = *(const bf8*)&xb[((size_t)(gr * W_ + col)) * C_IN + cin0 + sub * 8];
      } else {
        *dst = zer;
      }
    }
    if (tid < 64) {  // zero pad columns 0 and 65
      int row = tid >> 4;
      int col = ((tid >> 3) & 1) ? (BCOLS - 1) : 0;
      int s = tid & 7;
      *(bf8*)&Bs[(row * BCOLS + col) * AP + s * 8] = zer;
    }

    const ushort* wb0 = wbf + (size_t)cout0 * C_IN + cin0;
#pragma unroll
    for (int tap = 0; tap < 9; ++tap) {
      if (tap) __syncthreads();
      // ---- stage A tile: 128 cout x 64 cin of this tap ----
      const ushort* wt = wb0 + (size_t)tap * C_OUT * C_IN;
#pragma unroll
      for (int pass = 0; pass < 4; ++pass) {
        int row = pass * 32 + pr;
        *(bf8*)&As[row * AP + sub * 8] = *(const bf8*)&wt[(size_t)row * C_IN + sub * 8];
      }
      __syncthreads();

      const int kh = tap / 3, kw = tap % 3;
      const int bTap = (kh * BCOLS + kw) * AP;

      bf8 af[2][4], bfr[2][4];
#pragma unroll
      for (int ks = 0; ks < 2; ++ks) {
#pragma unroll
        for (int m = 0; m < 4; ++m)
          af[ks][m] = *(const bf8*)&As[aOff[m] + ks * 32];
#pragma unroll
        for (int n = 0; n < 4; ++n)
          bfr[ks][n] = *(const bf8*)&Bs[bOff[n] + bTap + ks * 32];
      }
#pragma unroll
      for (int ks = 0; ks < 2; ++ks)
#pragma unroll
        for (int m = 0; m < 4; ++m)
#pragma unroll
          for (int n = 0; n < 4; ++n)
            acc[m][n] = __builtin_amdgcn_mfma_f32_16x16x32_bf16(
                af[ks][m], bfr[ks][n], acc[m][n], 0, 0, 0);
    }
  }

  // ---- epilogue: demod scale + bias + leaky relu ----
  const int pbase = tile * 128 + wc * 64;
#pragma unroll
  for (int m = 0; m < 4; ++m) {
#pragma unroll
    for (int r = 0; r < 4; ++r) {
      int co = cout0 + wr * 64 + m * 16 + kg * 4 + r;
      float d = demod[b * C_OUT + co];
      float bi = bias[co];
      float* op = out + ((size_t)(b * C_OUT + co)) * HW_ + pbase + l15;
#pragma unroll
      for (int n = 0; n < 4; ++n) {
        float v = acc[m][n][r] * d + bi;
        op[n * 16] = v > 0.f ? v : 0.2f * v;
      }
    }
  }
}

extern "C" void kernel_launch(void* const* d_in, const int* in_sizes, int n_in,
                              void* d_out, int out_size, void* d_ws, size_t ws_size,
                              hipStream_t stream) {
  const float* x = (const float*)d_in[0];
  const float* lat = (const float*)d_in[1];
  const float* wgt = (const float*)d_in[2];
  const float* bias = (const float*)d_in[3];
  const float* fcw = (const float*)d_in[4];
  const float* fcb = (const float*)d_in[5];
  float* out = (float*)d_out;

  char* ws = (char*)d_ws;
  ushort* xm = (ushort*)ws;                                   // 33,554,432 B
  ushort* wbf = (ushort*)(ws + 33554432);                     //  4,718,592 B
  float* style = (float*)(ws + 33554432 + 4718592);           //     16,384 B
  float* wsq = (float*)(ws + 33554432 + 4718592 + 16384);     //  1,048,576 B
  float* dem = (float*)(ws + 33554432 + 4718592 + 16384 + 1048576);

  style_kernel<<<16, 256, 0, stream>>>(lat, fcw, fcb, style);
  wsq_kernel<<<1024, 256, 0, stream>>>(wgt, wsq);
  demod_kernel<<<16, 256, 0, stream>>>(style, wsq, dem);
  wcast_kernel<<<1024, 256, 0, stream>>>(wgt, wbf);
  xmod_kernel<<<dim3(8, 64, 8), 256, 0, stream>>>(x, style, xm);
  conv_kernel<<<dim3(4, 32, 8), 256, 0, stream>>>(xm, wbf, dem, bias, out);
}